// Round 1
// baseline (1212.908 us; speedup 1.0000x reference)
//
#include <hip/hip_runtime.h>

// Chambolle-Pock anisotropic TV prox.
// B=8, H=W=256, 200 iterations, fp32.
//
// Strategy (round 0): one fused kernel per iteration (200 launches total).
// Each thread owns one pixel and redundantly recomputes the neighbor
// p_new[i-1,j] / q_new[i,j-1] values it needs from OLD state, so a full
// (p,q,u,ubar) update needs only one kernel (no intra-iteration sync).
// State is double-buffered in d_ws: 2 bufs x 4 fields x 2MB = 16 MB.
// Iteration 0 is templated to read u=ubar=f, p=q=0 (no init kernel,
// no dependence on poisoned ws). Last iteration writes u to d_out.

#define Hc 256
#define Wc 256
#define Bc 8
#define NPIX (Bc * Hc * Wc)   // 524288

constexpr float TAU = 0.35355339f;
constexpr float SIG = 0.35355339f;
constexpr float INV1PT = 1.0f / (1.0f + 0.35355339f);

template <bool FIRST>
__global__ __launch_bounds__(256)
void tv_iter(const float* __restrict__ f, const float* __restrict__ lam,
             const float* __restrict__ ub_in, const float* __restrict__ p_in,
             const float* __restrict__ q_in, const float* __restrict__ u_in,
             float* __restrict__ ub_out, float* __restrict__ p_out,
             float* __restrict__ q_out, float* __restrict__ u_out)
{
    const int n = blockIdx.x * 256 + threadIdx.x;
    const int j = n & (Wc - 1);
    const int i = (n >> 8) & (Hc - 1);

    const float fv   = f[n];
    const float ub_c = FIRST ? fv : ub_in[n];

    float pc = 0.f, pu = 0.f, qc = 0.f, ql = 0.f;

    // p_new[i,j]  (exists for i < H-1), lamx[i,j] = lam[i+1,j]
    if (i < Hc - 1) {
        const float ub_dn = FIRST ? f[n + Wc] : ub_in[n + Wc];
        const float lx    = lam[n + Wc];
        const float v     = (FIRST ? 0.f : p_in[n]) + SIG * (ub_dn - ub_c);
        pc = fminf(fmaxf(v, -lx), lx);
    }
    // p_new[i-1,j] (exists for i > 0), lamx[i-1,j] = lam[i,j]
    if (i > 0) {
        const float ub_up = FIRST ? f[n - Wc] : ub_in[n - Wc];
        const float lx    = lam[n];
        const float v     = (FIRST ? 0.f : p_in[n - Wc]) + SIG * (ub_c - ub_up);
        pu = fminf(fmaxf(v, -lx), lx);
    }
    // q_new[i,j]  (exists for j < W-1), lamy[i,j] = lam[i,j+1]
    if (j < Wc - 1) {
        const float ub_rt = FIRST ? f[n + 1] : ub_in[n + 1];
        const float ly    = lam[n + 1];
        const float v     = (FIRST ? 0.f : q_in[n]) + SIG * (ub_rt - ub_c);
        qc = fminf(fmaxf(v, -ly), ly);
    }
    // q_new[i,j-1] (exists for j > 0), lamy[i,j-1] = lam[i,j]
    if (j > 0) {
        const float ub_lf = FIRST ? f[n - 1] : ub_in[n - 1];
        const float ly    = lam[n];
        const float v     = (FIRST ? 0.f : q_in[n - 1]) + SIG * (ub_c - ub_lf);
        ql = fminf(fmaxf(v, -ly), ly);
    }

    const float uo  = FIRST ? fv : u_in[n];
    // dxT(p)[i,j] = p[i-1,j] - p[i,j] ; dyT(q)[i,j] = q[i,j-1] - q[i,j]
    const float dv  = (pu - pc) + (ql - qc);
    const float un  = (uo - TAU * dv + TAU * fv) * INV1PT;

    if (i < Hc - 1) p_out[n] = pc;
    if (j < Wc - 1) q_out[n] = qc;
    u_out[n]  = un;
    ub_out[n] = 2.f * un - uo;
}

extern "C" void kernel_launch(void* const* d_in, const int* in_sizes, int n_in,
                              void* d_out, int out_size, void* d_ws, size_t ws_size,
                              hipStream_t stream)
{
    const float* f   = (const float*)d_in[0];
    const float* lam = (const float*)d_in[1];
    float* ws = (float*)d_ws;

    // double-buffered state in workspace: needs 8 * NPIX * 4 = 16 MB
    float* ub[2] = { ws + 0 * (size_t)NPIX, ws + 4 * (size_t)NPIX };
    float* pp[2] = { ws + 1 * (size_t)NPIX, ws + 5 * (size_t)NPIX };
    float* qq[2] = { ws + 2 * (size_t)NPIX, ws + 6 * (size_t)NPIX };
    float* uu[2] = { ws + 3 * (size_t)NPIX, ws + 7 * (size_t)NPIX };

    const int NITER = 200;
    dim3 grid(NPIX / 256), block(256);

    // t = 0: reads u=ubar=f, p=q=0; writes buffer 0
    tv_iter<true><<<grid, block, 0, stream>>>(f, lam,
                                              nullptr, nullptr, nullptr, nullptr,
                                              ub[0], pp[0], qq[0], uu[0]);
    for (int t = 1; t < NITER; ++t) {
        const int w = t & 1, r = w ^ 1;
        float* uout = (t == NITER - 1) ? (float*)d_out : uu[w];
        tv_iter<false><<<grid, block, 0, stream>>>(f, lam,
                                                   ub[r], pp[r], qq[r], uu[r],
                                                   ub[w], pp[w], qq[w], uout);
    }
}

// Round 3
// 363.611 us; speedup vs baseline: 3.3357x; 3.3357x over previous
//
#include <hip/hip_runtime.h>

// Chambolle-Pock anisotropic TV prox. B=8, H=W=256, 200 iters, fp32.
//
// Round 2: same temporal-fusion structure as round 1 (T=8 iters/launch,
// 25 launches, 256 blocks = 1/CU, region 48x80 w/ halo 8, interior 32x64)
// plus the boundary fix:
//   The reference pads p with a zero row ABOVE (p[-1]=0) and q with a zero
//   col LEFT (q[:,-1]=0). Because the clamp bounds are shifted
//   (lamx[i]=lam[i+1], lamy[j]=lam[j+1]), a phantom cell at gi==-1 clamps
//   with in-image lam[0] and produces p[-1]!=0 (same for gj+e==-1 and q).
//   Fix: zero ldn when gi<0 and ly[e] when gj+e<0. All other phantom cells
//   already get zero clamps via the out-of-image load guard.

#define Hc 256
#define Wc 256
#define Bc 8
#define NPIX (Bc * Hc * Wc)          // 524288

#define RROWS 48
#define RCOLS 80
#define IROWS 32
#define ICOLS 64
#define HALO  8
#define TITER 8
#define NLAUNCH 25
#define NGRP  (RROWS * (RCOLS / 4))  // 960 groups of 4 px
#define BLK   512
#define LSTR  84                      // LDS row stride (floats); 336B % 16 == 0

constexpr float TAUc = 0.35355339f;
constexpr float SIGc = 0.35355339f;
constexpr float Ac   = 1.0f / (1.0f + TAUc);  // 1/(1+tau)
constexpr float Bq   = TAUc * Ac;             // tau/(1+tau)

__device__ __forceinline__ float2 gld2(const float* p, int gi, int gj) {
    if ((unsigned)gi < (unsigned)Hc && (unsigned)gj < (unsigned)Wc)
        return *(const float2*)(p + (gi << 8) + gj);
    return make_float2(0.f, 0.f);
}
__device__ __forceinline__ float gld1(const float* p, int gi, int gj) {
    if ((unsigned)gi < (unsigned)Hc && (unsigned)gj < (unsigned)Wc)
        return p[(gi << 8) + gj];
    return 0.f;
}

template <bool FIRST, bool LAST>
__global__ __launch_bounds__(BLK)
void tv_tile(const float* __restrict__ f, const float* __restrict__ lam,
             const float* __restrict__ u_in, const float* __restrict__ ub_in,
             const float* __restrict__ p_in, const float* __restrict__ q_in,
             float* __restrict__ u_out, float* __restrict__ ub_out,
             float* __restrict__ p_out, float* __restrict__ q_out)
{
    __shared__ float s_ub[RROWS + 2][LSTR];
    __shared__ float s_p [RROWS + 2][LSTR];
    __shared__ float s_qe[RROWS][21];      // q edge col per group (+1 read offset)

    const int t   = threadIdx.x;
    const int blk = blockIdx.x;            // 0..255
    const int b   = blk >> 5;              // batch
    const int rem = blk & 31;
    const int ti  = rem >> 2;              // 0..7 row tile
    const int tj  = rem & 3;               // 0..3 col tile
    const int gi0 = ti * IROWS - HALO;
    const int gj0 = tj * ICOLS - HALO;

    const int boff = b * (Hc * Wc);
    const float* fb = f   + boff;
    const float* lb = lam + boff;

    float u[2][4], bf[2][4], ub[2][4], p[2][4], q[2][4], ly[2][4], ldn[2][4];
    int   rr[2], cg[2], c0[2];
    bool  act[2];

    // ---------------- load phase ----------------
    #pragma unroll
    for (int s = 0; s < 2; ++s) {
        const int gid = t + s * BLK;
        act[s] = (gid < NGRP);
        int row = gid / 20;                // region row
        int cgv = gid - row * 20;          // col group 0..19
        rr[s] = row; cg[s] = cgv; c0[s] = cgv * 4;
        if (!act[s]) continue;

        const int gi = gi0 + row;
        const int gj = gj0 + c0[s];

        float2 a0 = gld2(fb, gi, gj), a1 = gld2(fb, gi, gj + 2);
        float fv0 = a0.x, fv1 = a0.y, fv2 = a1.x, fv3 = a1.y;
        bf[s][0] = Bq * fv0; bf[s][1] = Bq * fv1;
        bf[s][2] = Bq * fv2; bf[s][3] = Bq * fv3;

        // lam own row (for q: lamy[j] = lam[j+1]) and row below (for p)
        a0 = gld2(lb, gi, gj); a1 = gld2(lb, gi, gj + 2);
        float le = gld1(lb, gi, gj + 4);
        ly[s][0] = a0.y; ly[s][1] = a1.x; ly[s][2] = a1.y; ly[s][3] = le;
        a0 = gld2(lb, gi + 1, gj); a1 = gld2(lb, gi + 1, gj + 2);
        ldn[s][0] = a0.x; ldn[s][1] = a0.y; ldn[s][2] = a1.x; ldn[s][3] = a1.y;

        // ---- phantom-pad fix ----
        // reference pads: p[-1,:]=0 (dxT) and q[:,-1]=0 (dyT). The shifted
        // clamp bounds (lam[i+1] / lam[j+1]) are in-image for gi==-1 /
        // gj+e==-1, so force them to zero there.
        if (gi < 0) { ldn[s][0] = ldn[s][1] = ldn[s][2] = ldn[s][3] = 0.f; }
        #pragma unroll
        for (int e = 0; e < 4; ++e) if (gj + e < 0) ly[s][e] = 0.f;

        if (FIRST) {
            u[s][0] = ub[s][0] = fv0; u[s][1] = ub[s][1] = fv1;
            u[s][2] = ub[s][2] = fv2; u[s][3] = ub[s][3] = fv3;
            p[s][0] = p[s][1] = p[s][2] = p[s][3] = 0.f;
            q[s][0] = q[s][1] = q[s][2] = q[s][3] = 0.f;
        } else {
            a0 = gld2(u_in + boff, gi, gj);  a1 = gld2(u_in + boff, gi, gj + 2);
            u[s][0] = a0.x; u[s][1] = a0.y; u[s][2] = a1.x; u[s][3] = a1.y;
            a0 = gld2(ub_in + boff, gi, gj); a1 = gld2(ub_in + boff, gi, gj + 2);
            ub[s][0] = a0.x; ub[s][1] = a0.y; ub[s][2] = a1.x; ub[s][3] = a1.y;
            a0 = gld2(p_in + boff, gi, gj);  a1 = gld2(p_in + boff, gi, gj + 2);
            p[s][0] = a0.x; p[s][1] = a0.y; p[s][2] = a1.x; p[s][3] = a1.y;
            a0 = gld2(q_in + boff, gi, gj);  a1 = gld2(q_in + boff, gi, gj + 2);
            q[s][0] = a0.x; q[s][1] = a0.y; q[s][2] = a1.x; q[s][3] = a1.y;
        }

        *(float4*)&s_ub[row + 1][c0[s]] = make_float4(ub[s][0], ub[s][1], ub[s][2], ub[s][3]);
        *(float4*)&s_p [row + 1][c0[s]] = make_float4(p[s][0], p[s][1], p[s][2], p[s][3]);
        s_qe[row][cgv + 1] = q[s][3];
    }
    __syncthreads();

    // ---------------- iteration loop ----------------
    for (int k = 0; k < TITER; ++k) {
        // step 1: p,q from ubar
        #pragma unroll
        for (int s = 0; s < 2; ++s) {
            if (!act[s]) continue;
            const int r = rr[s], col0 = c0[s];
            float4 ubdn = *(const float4*)&s_ub[r + 2][col0];
            float  ubre = s_ub[r + 1][col0 + 4];

            float v;
            v = fmaf(SIGc, ubdn.x - ub[s][0], p[s][0]); p[s][0] = fminf(fmaxf(v, -ldn[s][0]), ldn[s][0]);
            v = fmaf(SIGc, ubdn.y - ub[s][1], p[s][1]); p[s][1] = fminf(fmaxf(v, -ldn[s][1]), ldn[s][1]);
            v = fmaf(SIGc, ubdn.z - ub[s][2], p[s][2]); p[s][2] = fminf(fmaxf(v, -ldn[s][2]), ldn[s][2]);
            v = fmaf(SIGc, ubdn.w - ub[s][3], p[s][3]); p[s][3] = fminf(fmaxf(v, -ldn[s][3]), ldn[s][3]);

            v = fmaf(SIGc, ub[s][1] - ub[s][0], q[s][0]); q[s][0] = fminf(fmaxf(v, -ly[s][0]), ly[s][0]);
            v = fmaf(SIGc, ub[s][2] - ub[s][1], q[s][1]); q[s][1] = fminf(fmaxf(v, -ly[s][1]), ly[s][1]);
            v = fmaf(SIGc, ub[s][3] - ub[s][2], q[s][2]); q[s][2] = fminf(fmaxf(v, -ly[s][2]), ly[s][2]);
            v = fmaf(SIGc, ubre     - ub[s][3], q[s][3]); q[s][3] = fminf(fmaxf(v, -ly[s][3]), ly[s][3]);

            *(float4*)&s_p[r + 1][col0] = make_float4(p[s][0], p[s][1], p[s][2], p[s][3]);
            s_qe[r][cg[s] + 1] = q[s][3];
        }
        __syncthreads();

        // step 2: u, ubar from p,q
        #pragma unroll
        for (int s = 0; s < 2; ++s) {
            if (!act[s]) continue;
            const int r = rr[s], col0 = c0[s];
            float4 pup = *(const float4*)&s_p[r][col0];
            float  qe  = s_qe[r][cg[s]];

            float pu[4] = {pup.x, pup.y, pup.z, pup.w};
            float ql[4] = {qe, q[s][0], q[s][1], q[s][2]};
            #pragma unroll
            for (int e = 0; e < 4; ++e) {
                float dv = (pu[e] - p[s][e]) + (ql[e] - q[s][e]);
                float un = fmaf(Ac, u[s][e], bf[s][e]);
                un = fmaf(-Bq, dv, un);
                float ubn = 2.f * un - u[s][e];
                u[s][e] = un; ub[s][e] = ubn;
            }
            *(float4*)&s_ub[r + 1][col0] = make_float4(ub[s][0], ub[s][1], ub[s][2], ub[s][3]);
        }
        __syncthreads();
    }

    // ---------------- store phase (interior only) ----------------
    #pragma unroll
    for (int s = 0; s < 2; ++s) {
        if (!act[s]) continue;
        const int r = rr[s], cgv = cg[s];
        if (r < HALO || r >= HALO + IROWS || cgv < 2 || cgv >= 18) continue;
        const int gi = gi0 + r;
        const int gj = gj0 + c0[s];
        const int idx = boff + (gi << 8) + gj;
        if (LAST) {
            *(float4*)&u_out[idx] = make_float4(u[s][0], u[s][1], u[s][2], u[s][3]);
        } else {
            *(float4*)&u_out [idx] = make_float4(u[s][0], u[s][1], u[s][2], u[s][3]);
            *(float4*)&ub_out[idx] = make_float4(ub[s][0], ub[s][1], ub[s][2], ub[s][3]);
            *(float4*)&p_out [idx] = make_float4(p[s][0], p[s][1], p[s][2], p[s][3]);
            *(float4*)&q_out [idx] = make_float4(q[s][0], q[s][1], q[s][2], q[s][3]);
        }
    }
}

extern "C" void kernel_launch(void* const* d_in, const int* in_sizes, int n_in,
                              void* d_out, int out_size, void* d_ws, size_t ws_size,
                              hipStream_t stream)
{
    const float* f   = (const float*)d_in[0];
    const float* lam = (const float*)d_in[1];
    float* ws = (float*)d_ws;

    // two state sets (u, ub, p, q) for ping-pong: 8 * NPIX floats = 16 MB
    float* U [2] = { ws + 0 * (size_t)NPIX, ws + 4 * (size_t)NPIX };
    float* UB[2] = { ws + 1 * (size_t)NPIX, ws + 5 * (size_t)NPIX };
    float* P [2] = { ws + 2 * (size_t)NPIX, ws + 6 * (size_t)NPIX };
    float* Q [2] = { ws + 3 * (size_t)NPIX, ws + 7 * (size_t)NPIX };

    dim3 grid(256), block(BLK);

    // launch 0: FIRST (state = f, 0), writes set 0
    tv_tile<true, false><<<grid, block, 0, stream>>>(
        f, lam, nullptr, nullptr, nullptr, nullptr,
        U[0], UB[0], P[0], Q[0]);

    for (int l = 1; l < NLAUNCH - 1; ++l) {
        const int w = l & 1, r = w ^ 1;
        tv_tile<false, false><<<grid, block, 0, stream>>>(
            f, lam, U[r], UB[r], P[r], Q[r],
            U[w], UB[w], P[w], Q[w]);
    }

    // last launch: reads set written by l=23 (set 1), writes u -> d_out
    tv_tile<false, true><<<grid, block, 0, stream>>>(
        f, lam, U[1], UB[1], P[1], Q[1],
        (float*)d_out, nullptr, nullptr, nullptr);
}